// Round 1
// baseline (1123.262 us; speedup 1.0000x reference)
//
#include <hip/hip_runtime.h>
#include <math.h>

// ---------------------------------------------------------------------------
// Mlp_moe: fused shared-MLP over all 582 tokens (patch out + e0 for cls rows),
// small MoE path for cls tokens, top-2 gating, in-place mix into d_out.
// All GEMMs in bf16 MFMA (16x16x32), fp32 accumulate.
// ---------------------------------------------------------------------------

typedef unsigned short bfu;                                   // bf16 bits
typedef __attribute__((ext_vector_type(8))) short bf16x8;     // MFMA A/B frag
typedef __attribute__((ext_vector_type(4))) float f32x4;      // MFMA C/D frag

#define GLD_LDS16(g, l)                                                        \
  __builtin_amdgcn_global_load_lds(                                            \
      (const __attribute__((address_space(1))) void*)(g),                      \
      (__attribute__((address_space(3))) void*)(l), 16, 0, 0)

__device__ __forceinline__ bfu f2bf(float f) {
  unsigned int u = __float_as_uint(f);
  u += 0x7FFFu + ((u >> 16) & 1u);   // RNE
  return (bfu)(u >> 16);
}
__device__ __forceinline__ float gelu_exact(float v) {
  return 0.5f * v * (1.0f + erff(v * 0.70710678118654752440f));
}

// ---------------------------------------------------------------------------
// Core MFMA GEMM tile:  C[BM x 128] = A[BM x K] * B^T[128 x K] (+bias, gelu)
// A row-major MxK (lda=K), Bt row-major NxK (ldb=K).
// LDS tiles staged via global_load_lds with XOR-swizzled SOURCE (slot^(row&7))
// so ds_read_b128 fragments at 128B row stride are ~conflict-free (G4 fix).
// ---------------------------------------------------------------------------
template <int BM, int WC, int MF, int NF, bool GELU, bool OUTBF>
__device__ __forceinline__ void gemm_tile(
    bfu* As, bfu* Bs,
    const bfu* __restrict__ A,    // tile origin (already + m0*K)
    const bfu* __restrict__ Bt,   // tile origin (already + n0*K)
    const float* __restrict__ bias, // already + n0
    void* __restrict__ out,       // tile origin (already + m0*ldo + n0, typed)
    int K, int ldo) {
  const int tid  = threadIdx.x;
  const int lane = tid & 63;
  const int wv   = tid >> 6;                // 0..3
  const int wm   = (wv / WC) * (MF * 16);   // wave row offset in tile
  const int wn   = (wv % WC) * (NF * 16);   // wave col offset in tile

  const f32x4 fzero = {0.f, 0.f, 0.f, 0.f};
  f32x4 acc[MF][NF];
#pragma unroll
  for (int m = 0; m < MF; ++m)
#pragma unroll
    for (int n = 0; n < NF; ++n) acc[m][n] = fzero;

  // staging geometry: 256 thr * 16B = 32 rows of 64 bf16 per issue
  const int srow  = tid >> 3;                  // 0..31
  const int gslot = (tid & 7) ^ (srow & 7);    // pre-swizzled source 16B slot
  const bfu* ga = A  + (size_t)srow * K + gslot * 8;
  const bfu* gb = Bt + (size_t)srow * K + gslot * 8;

  const int lrow = lane & 15;
  const int lks  = lane >> 4;                  // k 16B-slot base within 32-k step

  for (int kt = 0; kt < K; kt += 64) {
#pragma unroll
    for (int i = 0; i < BM / 32; ++i)
      GLD_LDS16(ga + kt + (size_t)i * 32 * K, As + i * 2048 + wv * 512);
#pragma unroll
    for (int i = 0; i < 4; ++i)
      GLD_LDS16(gb + kt + (size_t)i * 32 * K, Bs + i * 2048 + wv * 512);
    __syncthreads();   // drains vmcnt (compiler-inserted) then barrier

#pragma unroll
    for (int kk = 0; kk < 2; ++kk) {          // two 32-wide k substeps
      bf16x8 af[MF], bfr[NF];
#pragma unroll
      for (int m = 0; m < MF; ++m) {
        int row  = wm + m * 16 + lrow;
        int slot = (kk * 4 + lks) ^ (row & 7);
        af[m] = *(const bf16x8*)(As + row * 64 + slot * 8);
      }
#pragma unroll
      for (int n = 0; n < NF; ++n) {
        int row  = wn + n * 16 + lrow;
        int slot = (kk * 4 + lks) ^ (row & 7);
        bfr[n] = *(const bf16x8*)(Bs + row * 64 + slot * 8);
      }
#pragma unroll
      for (int m = 0; m < MF; ++m)
#pragma unroll
        for (int n = 0; n < NF; ++n)
          acc[m][n] = __builtin_amdgcn_mfma_f32_16x16x32_bf16(af[m], bfr[n],
                                                              acc[m][n], 0, 0, 0);
    }
    __syncthreads();
  }

  // epilogue: D mapping col=lane&15, row=(lane>>4)*4+r  (m89/m91 verified)
  const int rbase = (lane >> 4) * 4;
#pragma unroll
  for (int n = 0; n < NF; ++n) {
    int col = wn + n * 16 + lrow;
    float bv = bias[col];
#pragma unroll
    for (int m = 0; m < MF; ++m) {
#pragma unroll
      for (int r = 0; r < 4; ++r) {
        int row = wm + m * 16 + rbase + r;
        float v = acc[m][n][r] + bv;
        if (GELU) v = gelu_exact(v);
        if (OUTBF)
          ((bfu*)out)[(size_t)row * ldo + col] = f2bf(v);
        else
          ((float*)out)[(size_t)row * ldo + col] = v;
      }
    }
  }
}

// -------------------- GEMM kernel wrappers --------------------
template <bool GELU, bool OUTBF>
__global__ __launch_bounds__(256) void gemm128_kernel(
    const bfu* __restrict__ A, const bfu* __restrict__ Bt,
    const float* __restrict__ bias, void* __restrict__ out, int K, int ldo) {
  __shared__ bfu As[128 * 64];
  __shared__ bfu Bs[128 * 64];
  size_t m0 = (size_t)blockIdx.x * 128, n0 = (size_t)blockIdx.y * 128;
  gemm_tile<128, 2, 4, 4, GELU, OUTBF>(
      As, Bs, A + m0 * K, Bt + n0 * K, bias + n0,
      (void*)((char*)out + ((size_t)m0 * ldo + n0) * (OUTBF ? 2 : 4)), K, ldo);
}

// hid_t = gelu(cls_t @ W_in[t%5] + b_in[t%5])  -> bf16 [6][64][3072]
__global__ __launch_bounds__(256) void hidc_kernel(
    const bfu* __restrict__ clsb, const bfu* __restrict__ WinT,
    const float* __restrict__ b_in, bfu* __restrict__ hidc) {
  __shared__ bfu As[64 * 64];
  __shared__ bfu Bs[128 * 64];
  int t = blockIdx.y, a = t % 5, nt = blockIdx.x;
  gemm_tile<64, 4, 4, 2, true, true>(
      As, Bs, clsb + (size_t)t * 64 * 768,
      WinT + (size_t)a * 3072 * 768 + (size_t)nt * 128 * 768,
      b_in + a * 3072 + nt * 128,
      (void*)(hidc + (size_t)t * 64 * 3072 + nt * 128), 768, 3072);
}

// allo_t = hid_t @ [W_out^T concat over o] + b_out  -> f32 [6][64][3840]
__global__ __launch_bounds__(256) void allo_kernel(
    const bfu* __restrict__ hidc, const bfu* __restrict__ WoutT,
    const float* __restrict__ b_out, float* __restrict__ allo) {
  __shared__ bfu As[64 * 64];
  __shared__ bfu Bs[128 * 64];
  int t = blockIdx.y, nt = blockIdx.x;
  gemm_tile<64, 4, 4, 2, false, false>(
      As, Bs, hidc + (size_t)t * 64 * 3072,
      WoutT + (size_t)nt * 128 * 3072, b_out + nt * 128,
      (void*)(allo + (size_t)t * 64 * 3840 + nt * 128), 3072, 3840);
}

// -------------------- conversion / layout kernels --------------------
__global__ __launch_bounds__(256) void cvt_f32_bf16_kernel(
    const float* __restrict__ in, bfu* __restrict__ out, int n4) {
  int stride = gridDim.x * blockDim.x;
  for (int i = blockIdx.x * blockDim.x + threadIdx.x; i < n4; i += stride) {
    float4 v = ((const float4*)in)[i];
    ushort4 o;
    o.x = f2bf(v.x); o.y = f2bf(v.y); o.z = f2bf(v.z); o.w = f2bf(v.w);
    ((ushort4*)out)[i] = o;
  }
}

// in f32 [Z][R][C] -> out bf16 [Z][C][R]
__global__ __launch_bounds__(256) void transpose_kernel(
    const float* __restrict__ in, bfu* __restrict__ out, int R, int C) {
  __shared__ float tile[32][33];
  int z = blockIdx.z;
  const float* src = in + (size_t)z * R * C;
  bfu* dst = out + (size_t)z * R * C;
  int c0 = blockIdx.x * 32, r0 = blockIdx.y * 32;
  int tx = threadIdx.x, ty = threadIdx.y;  // 32 x 8
#pragma unroll
  for (int j = 0; j < 32; j += 8)
    tile[ty + j][tx] = src[(size_t)(r0 + ty + j) * C + c0 + tx];
  __syncthreads();
#pragma unroll
  for (int j = 0; j < 32; j += 8)
    dst[(size_t)(c0 + ty + j) * R + r0 + tx] = f2bf(tile[tx][ty + j]);
}

// clsb[t][b][d] = bf16(x[b][t][d])   (t-major so each task is a 64x768 block)
__global__ __launch_bounds__(256) void build_clsb_kernel(
    const float* __restrict__ x, bfu* __restrict__ clsb) {
  int i = blockIdx.x * 256 + threadIdx.x;  // 6*64*768 total
  int d = i % 768, bt = i / 768;
  int b = bt % 64, t = bt / 64;
  clsb[i] = f2bf(x[((size_t)b * 582 + t) * 768 + d]);
}

// top-2 renormalized softmax gate weights gw[b*6+t][0..5]
__global__ __launch_bounds__(64) void gate_kernel(
    const float* __restrict__ x, const float* __restrict__ Wg,
    float* __restrict__ gw) {
  int bt = blockIdx.x;            // b*6 + t
  int b = bt / 6, t = bt % 6;
  const float* xr = x + ((size_t)b * 582 + t) * 768;
  const float* wg = Wg + (size_t)t * 768 * 6;
  int lane = threadIdx.x;
  float z[6] = {0.f, 0.f, 0.f, 0.f, 0.f, 0.f};
  for (int d = lane; d < 768; d += 64) {
    float xv = xr[d];
#pragma unroll
    for (int o = 0; o < 6; ++o) z[o] += xv * wg[d * 6 + o];
  }
#pragma unroll
  for (int o = 0; o < 6; ++o)
#pragma unroll
    for (int s = 32; s > 0; s >>= 1) z[o] += __shfl_down(z[o], s);
  if (lane == 0) {
    int i1 = 0;
#pragma unroll
    for (int o = 1; o < 6; ++o) if (z[o] > z[i1]) i1 = o;
    int i2 = -1;
#pragma unroll
    for (int o = 0; o < 6; ++o) {
      if (o == i1) continue;
      if (i2 < 0 || z[o] > z[i2]) i2 = o;
    }
    // renormalized top-2 softmax == softmax over the two logits
    float w1 = 1.f / (1.f + expf(z[i2] - z[i1]));
    float o6[6] = {0.f, 0.f, 0.f, 0.f, 0.f, 0.f};
    o6[i1] = w1; o6[i2] = 1.f - w1;
#pragma unroll
    for (int o = 0; o < 6; ++o) gw[bt * 6 + o] = o6[o];
  }
}

// cls rows of d_out currently hold e0; replace with gated mixture
__global__ __launch_bounds__(256) void mix_kernel(
    float* __restrict__ out, const float* __restrict__ allo,
    const float* __restrict__ gw) {
  int bt = blockIdx.x;
  int b = bt / 6, t = bt % 6;
  float g[6];
#pragma unroll
  for (int o = 0; o < 6; ++o) g[o] = gw[bt * 6 + o];
  float* orow = out + ((size_t)b * 582 + t) * 768;
  const float* arow = allo + ((size_t)t * 64 + b) * 3840;
  for (int d = threadIdx.x; d < 768; d += 256) {
    float v = g[0] * orow[d];
#pragma unroll
    for (int o = 0; o < 5; ++o) v += g[o + 1] * arow[o * 768 + d];
    orow[d] = v;
  }
}

// ---------------------------------------------------------------------------
extern "C" void kernel_launch(void* const* d_in, const int* in_sizes, int n_in,
                              void* d_out, int out_size, void* d_ws,
                              size_t ws_size, hipStream_t stream) {
  const float* x     = (const float*)d_in[0];
  const float* W1    = (const float*)d_in[1];
  const float* b1    = (const float*)d_in[2];
  const float* W2    = (const float*)d_in[3];
  const float* b2    = (const float*)d_in[4];
  const float* W_in  = (const float*)d_in[5];
  const float* b_in  = (const float*)d_in[6];
  const float* W_out = (const float*)d_in[7];
  const float* b_out = (const float*)d_in[8];
  const float* Wg    = (const float*)d_in[9];
  float* out = (float*)d_out;

  // sizes
  constexpr int M = 37248;           // 64*582 rows, = 291*128
  constexpr int CHUNK_TILES = 97;    // 291/3
  constexpr int CHUNK_ROWS  = CHUNK_TILES * 128;  // 12416
  constexpr size_t SZ_XB    = (size_t)M * 768 * 2;
  constexpr size_t SZ_W1T   = (size_t)3072 * 768 * 2;
  constexpr size_t SZ_W2T   = (size_t)768 * 3072 * 2;
  constexpr size_t SZ_WINT  = (size_t)5 * 3072 * 768 * 2;
  constexpr size_t SZ_WOUTT = (size_t)5 * 768 * 3072 * 2;
  constexpr size_t SZ_HID   = (size_t)CHUNK_ROWS * 3072 * 2;
  constexpr size_t SZ_CLSB  = (size_t)6 * 64 * 768 * 2;
  constexpr size_t SZ_HIDC  = (size_t)6 * 64 * 3072 * 2;
  constexpr size_t SZ_ALLO  = (size_t)6 * 64 * 3840 * 4;
  constexpr size_t SZ_GW    = (size_t)384 * 6 * 4;

  char* ws = (char*)d_ws;
  size_t off = 0;
  auto take = [&](size_t bytes) {
    char* p = ws + off;
    off += (bytes + 255) & ~(size_t)255;
    return p;
  };
  bfu*   xb    = (bfu*)take(SZ_XB);
  bfu*   W1t   = (bfu*)take(SZ_W1T);
  bfu*   W2t   = (bfu*)take(SZ_W2T);
  bfu*   WinT  = (bfu*)take(SZ_WINT);
  bfu*   WoutT = (bfu*)take(SZ_WOUTT);
  bfu*   hid   = (bfu*)take(SZ_HID);
  bfu*   clsb  = (bfu*)take(SZ_CLSB);
  bfu*   hidc  = (bfu*)take(SZ_HIDC);
  float* allo  = (float*)take(SZ_ALLO);
  float* gw    = (float*)take(SZ_GW);
  if (ws_size < off) return;  // workspace too small — fail loudly via mismatch

  // --- layout/conversion passes ---
  cvt_f32_bf16_kernel<<<2048, 256, 0, stream>>>(x, xb, M * 768 / 4);
  transpose_kernel<<<dim3(96, 24, 1), dim3(32, 8), 0, stream>>>(W1, W1t, 768, 3072);
  transpose_kernel<<<dim3(24, 96, 1), dim3(32, 8), 0, stream>>>(W2, W2t, 3072, 768);
  transpose_kernel<<<dim3(96, 24, 5), dim3(32, 8), 0, stream>>>(W_in, WinT, 768, 3072);
  transpose_kernel<<<dim3(24, 96, 5), dim3(32, 8), 0, stream>>>(W_out, WoutT, 3072, 768);
  build_clsb_kernel<<<(6 * 64 * 768) / 256, 256, 0, stream>>>(x, clsb);
  gate_kernel<<<384, 64, 0, stream>>>(x, Wg, gw);

  // --- big shared MLP over all tokens (patch output + e0 for cls rows) ---
  for (int c = 0; c < 3; ++c) {
    const bfu* Ac = xb + (size_t)c * CHUNK_ROWS * 768;
    float* Oc = out + (size_t)c * CHUNK_ROWS * 768;
    gemm128_kernel<true, true><<<dim3(CHUNK_TILES, 24), 256, 0, stream>>>(
        Ac, W1t, b1, (void*)hid, 768, 3072);
    gemm128_kernel<false, false><<<dim3(CHUNK_TILES, 6), 256, 0, stream>>>(
        hid, W2t, b2, (void*)Oc, 3072, 768);
  }

  // --- MoE cls path ---
  hidc_kernel<<<dim3(24, 6), 256, 0, stream>>>(clsb, WinT, b_in, hidc);
  allo_kernel<<<dim3(30, 6), 256, 0, stream>>>(hidc, WoutT, b_out, allo);
  mix_kernel<<<384, 256, 0, stream>>>(out, allo, gw);
}